// Round 8
// baseline (206.528 us; speedup 1.0000x reference)
//
#include <hip/hip_runtime.h>

typedef __bf16 bf16_t;
typedef bf16_t bf16x8 __attribute__((ext_vector_type(8)));
typedef bf16_t bf16x4 __attribute__((ext_vector_type(4)));
typedef float f32x4 __attribute__((ext_vector_type(4)));
typedef float fv4 __attribute__((ext_vector_type(4)));   // for nontemporal builtins

#define MFMA __builtin_amdgcn_mfma_f32_16x16x32_bf16
#define SWZ(row, off) ((off) ^ (((row) & 7) << 4))

// ws: weights in MFMA A-fragment order: elem((t*8+kk)*512 + lane*8 + j)
//   = W[k = kk*32 + (lane>>4)*8 + j][col = t*16 + (lane&15)]
#define F_W1A   0        // 256 cols (16 tiles)
#define F_W2A   65536    // 256 cols
#define F_W1B   131072   // 512 cols (tile idx = agent*4 + qhtile)
#define F_W2B   262144   // 64 cols (4 tiles)
#define F_WB1   278528   // 64 cols
#define F_WB2A  294912   // 64 cols

__device__ __forceinline__ bf16x8 cvt8(fv4 a, fv4 b) {
  bf16x8 v;
  v[0]=(bf16_t)a[0]; v[1]=(bf16_t)a[1]; v[2]=(bf16_t)a[2]; v[3]=(bf16_t)a[3];
  v[4]=(bf16_t)b[0]; v[5]=(bf16_t)b[1]; v[6]=(bf16_t)b[2]; v[7]=(bf16_t)b[3];
  return v;
}

__global__ __launch_bounds__(256) void cvt_frag(
    const float* __restrict__ W1a, const float* __restrict__ W2a,
    const float* __restrict__ W1b, const float* __restrict__ W2b,
    const float* __restrict__ Wb1, const float* __restrict__ Wb2a,
    bf16_t* __restrict__ ws)
{
  int gid = blockIdx.x * 256 + threadIdx.x;
  const float* src; int start, base, nout;
  if (gid < 8192)       { src = W1a;  start = 0;     base = F_W1A;  nout = 256; }
  else if (gid < 16384) { src = W2a;  start = 8192;  base = F_W2A;  nout = 256; }
  else if (gid < 32768) { src = W1b;  start = 16384; base = F_W1B;  nout = 512; }
  else if (gid < 34816) { src = W2b;  start = 32768; base = F_W2B;  nout = 64;  }
  else if (gid < 36864) { src = Wb1;  start = 34816; base = F_WB1;  nout = 64;  }
  else                  { src = Wb2a; start = 36864; base = F_WB2A; nout = 64;  }
  int local = gid - start;
  int t = local >> 9, kk = (local >> 6) & 7, l = local & 63;
  int n  = t * 16 + (l & 15);
  int k0 = kk * 32 + (l >> 4) * 8;
  bf16x8 v;
  #pragma unroll
  for (int j = 0; j < 8; ++j) v[j] = (bf16_t)src[(k0 + j) * nout + n];
  *(bf16x8*)(ws + base + (size_t)local * 8) = v;
}

#define FRAG(base, tile, kk) \
  (*(const bf16x8*)(ws + (base) + ((size_t)(((tile) * 8 + (kk))) << 9) + lane * 8))

// fused kernel: 1024 thr (16 waves), 256 rows/block, 4 x 64-row tiles.
// 16 waves/CU requires <=128 unified regs/wave -- every phase audited for that.
__global__ __launch_bounds__(1024, 4) void qmix_f3(
    const float* __restrict__ s, const float* __restrict__ q,
    const bf16_t* __restrict__ ws,
    const float* __restrict__ b1a, const float* __restrict__ b2a,
    const float* __restrict__ b1b, const float* __restrict__ b2b,
    const float* __restrict__ bb1, const float* __restrict__ bb2a,
    const float* __restrict__ Wb2b, const float* __restrict__ bb2b,
    float* __restrict__ out)
{
  __shared__ __align__(16) char sT[64 * 512];      // 32K, s tile bf16 swizzled
  __shared__ __align__(16) char h1T[64 * 512];     // 32K
  __shared__ __align__(16) char h2T[64 * 512];     // 32K
  __shared__ __align__(16) char b1T[64 * 128];     // 8K  [row][qh] bf16
  __shared__ __align__(16) char w2T[64 * 128];     // 8K
  __shared__ __align__(16) char hidT[64 * 128];    // 8K  post-elu hidden bf16
  __shared__ float b2part[4][64];                  // 1K   -> 121K total

  const int tid = threadIdx.x, wave = tid >> 6, lane = tid & 63;
  const int r16 = lane & 15, g = lane >> 4;
  const int wid = wave & 7, hp = wave >> 3;        // ph1 shard
  const int tq = wave & 3, hq = wave >> 2;         // ph2 shard
  const int row0 = blockIdx.x * 256;
  const int srow = tid >> 4, sc = tid & 15;        // staging: 64 rows x 16 chunks

  // prologue: stage s tile 0 (nontemporal: s is stream-once)
  {
    const fv4* p = (const fv4*)(s + (size_t)(row0 + srow) * 256 + sc * 16);
    fv4 a0 = __builtin_nontemporal_load(p);
    fv4 a1 = __builtin_nontemporal_load(p + 1);
    fv4 a2 = __builtin_nontemporal_load(p + 2);
    fv4 a3 = __builtin_nontemporal_load(p + 3);
    *(bf16x8*)(&sT[srow * 512 + SWZ(srow, sc * 32)])      = cvt8(a0, a1);
    *(bf16x8*)(&sT[srow * 512 + SWZ(srow, sc * 32 + 16)]) = cvt8(a2, a3);
  }
  __syncthreads();

  const float bb2b0 = bb2b[0];
  const int smBase = (wid < 4) ? (F_WB1 + wid * 4096) : (F_WB2A + (wid - 4) * 4096);

  #pragma unroll 1
  for (int rt = 0; rt < 4; ++rt) {
    const int rowt = row0 + rt * 64;
    // ======== phase 1, group A: 4 col-tiles x 2 halves (32 acc regs)
    {
      f32x4 acc[4][2];
      #pragma unroll
      for (int t = 0; t < 4; ++t) { acc[t][0] = (f32x4)0.f; acc[t][1] = (f32x4)0.f; }
      #pragma unroll 4
      for (int kk = 0; kk < 8; ++kk) {
        bf16x8 A0 = FRAG(F_W1A, wid, kk);
        bf16x8 A1 = FRAG(F_W1A, wid + 8, kk);
        bf16x8 A2 = FRAG(F_W2A, wid, kk);
        bf16x8 A3 = FRAG(F_W2A, wid + 8, kk);
        #pragma unroll
        for (int hh = 0; hh < 2; ++hh) {
          int rr = hp * 32 + hh * 16 + r16;
          bf16x8 B = *(const bf16x8*)(&sT[rr * 512 + SWZ(rr, kk * 64 + g * 16)]);
          acc[0][hh] = MFMA(A0, B, acc[0][hh], 0, 0, 0);
          acc[1][hh] = MFMA(A1, B, acc[1][hh], 0, 0, 0);
          acc[2][hh] = MFMA(A2, B, acc[2][hh], 0, 0, 0);
          acc[3][hh] = MFMA(A3, B, acc[3][hh], 0, 0, 0);
        }
      }
      #pragma unroll
      for (int t8 = 0; t8 < 2; ++t8) {
        float4 bh1 = *(const float4*)(b1a + (wid + t8 * 8) * 16 + 4 * g);
        float4 bh2 = *(const float4*)(b2a + (wid + t8 * 8) * 16 + 4 * g);
        #pragma unroll
        for (int hh = 0; hh < 2; ++hh) {
          int rr = hp * 32 + hh * 16 + r16;
          f32x4 x1 = acc[t8][hh], x2 = acc[2 + t8][hh];
          bf16x4 v1, v2;
          v1[0]=(bf16_t)fmaxf(x1[0]+bh1.x,0.f); v1[1]=(bf16_t)fmaxf(x1[1]+bh1.y,0.f);
          v1[2]=(bf16_t)fmaxf(x1[2]+bh1.z,0.f); v1[3]=(bf16_t)fmaxf(x1[3]+bh1.w,0.f);
          v2[0]=(bf16_t)fmaxf(x2[0]+bh2.x,0.f); v2[1]=(bf16_t)fmaxf(x2[1]+bh2.y,0.f);
          v2[2]=(bf16_t)fmaxf(x2[2]+bh2.z,0.f); v2[3]=(bf16_t)fmaxf(x2[3]+bh2.w,0.f);
          *(bf16x4*)(&h1T[rr * 512 + SWZ(rr, (wid + t8 * 8) * 32 + 8 * g)]) = v1;
          *(bf16x4*)(&h2T[rr * 512 + SWZ(rr, (wid + t8 * 8) * 32 + 8 * g)]) = v2;
        }
      }
    }
    // ======== phase 1, group B: small tile x 2 halves (8 acc regs)
    {
      f32x4 aS[2]; aS[0] = (f32x4)0.f; aS[1] = (f32x4)0.f;
      #pragma unroll
      for (int kk = 0; kk < 8; ++kk) {
        bf16x8 A = *(const bf16x8*)(ws + smBase + ((size_t)kk << 9) + lane * 8);
        #pragma unroll
        for (int hh = 0; hh < 2; ++hh) {
          int rr = hp * 32 + hh * 16 + r16;
          bf16x8 B = *(const bf16x8*)(&sT[rr * 512 + SWZ(rr, kk * 64 + g * 16)]);
          aS[hh] = MFMA(A, B, aS[hh], 0, 0, 0);
        }
      }
      if (wid < 4) {
        float4 bb = *(const float4*)(bb1 + wid * 16 + 4 * g);
        #pragma unroll
        for (int hh = 0; hh < 2; ++hh) {
          int rr = hp * 32 + hh * 16 + r16;
          bf16x4 o;
          o[0]=(bf16_t)(aS[hh][0]+bb.x); o[1]=(bf16_t)(aS[hh][1]+bb.y);
          o[2]=(bf16_t)(aS[hh][2]+bb.z); o[3]=(bf16_t)(aS[hh][3]+bb.w);
          *(bf16x4*)(&b1T[rr * 128 + wid * 32 + 8 * g]) = o;
        }
      } else {
        float4 ba = *(const float4*)(bb2a + (wid - 4) * 16 + 4 * g);
        float4 wv = *(const float4*)(Wb2b + (wid - 4) * 16 + 4 * g);
        #pragma unroll
        for (int hh = 0; hh < 2; ++hh) {
          int rr = hp * 32 + hh * 16 + r16;
          f32x4 x = aS[hh];
          float part = fmaxf(x[0]+ba.x,0.f)*wv.x + fmaxf(x[1]+ba.y,0.f)*wv.y
                     + fmaxf(x[2]+ba.z,0.f)*wv.z + fmaxf(x[3]+ba.w,0.f)*wv.w;
          part += __shfl_xor(part, 16); part += __shfl_xor(part, 32);
          if (lane < 16) b2part[wid - 4][rr] = part;
        }
      }
    }
    __syncthreads();  // A: h1T/h2T/b1T/b2part ready; sT free

    // issue next s-tile loads early (latency hides under ph2 MFMAs)
    fv4 L0, L1, L2, L3;
    if (rt < 3) {
      const fv4* p = (const fv4*)(s + (size_t)(rowt + 64 + srow) * 256 + sc * 16);
      L0 = __builtin_nontemporal_load(p);
      L1 = __builtin_nontemporal_load(p + 1);
      L2 = __builtin_nontemporal_load(p + 2);
      L3 = __builtin_nontemporal_load(p + 3);
    }
    // ======== phase 2a: w2 = |h2 @ W2b + b2b|  (wave -> tile tq, half hq)
    {
      const int rr = hq * 16 + r16;
      f32x4 av = (f32x4)0.f;
      #pragma unroll
      for (int kk = 0; kk < 8; ++kk) {
        bf16x8 A = FRAG(F_W2B, tq, kk);
        bf16x8 B = *(const bf16x8*)(&h2T[rr * 512 + SWZ(rr, kk * 64 + g * 16)]);
        av = MFMA(A, B, av, 0, 0, 0);
      }
      float4 bv = *(const float4*)(b2b + tq * 16 + 4 * g);
      bf16x4 o;
      o[0]=(bf16_t)fabsf(av[0]+bv.x); o[1]=(bf16_t)fabsf(av[1]+bv.y);
      o[2]=(bf16_t)fabsf(av[2]+bv.z); o[3]=(bf16_t)fabsf(av[3]+bv.w);
      *(bf16x4*)(&w2T[rr * 128 + tq * 32 + 8 * g]) = o;
    }
    // ======== phase 2b: hidden(t=tq, half=hq) = sum_a q[a]*|h1@W1b+b1b|
    {
      const int row = hq * 16 + r16;
      // hoist the 8 h1 B-frags (64 regs, the audited peak)
      bf16x8 B[8];
      #pragma unroll
      for (int kk = 0; kk < 8; ++kk)
        B[kk] = *(const bf16x8*)(&h1T[row * 512 + SWZ(row, kk * 64 + g * 16)]);
      f32x4 hid = (f32x4)0.f;
      #pragma unroll 2
      for (int a = 0; a < 8; ++a) {
        f32x4 a2 = (f32x4)0.f;
        #pragma unroll
        for (int kk = 0; kk < 8; ++kk) {
          bf16x8 A = FRAG(F_W1B, a * 4 + tq, kk);
          a2 = MFMA(A, B[kk], a2, 0, 0, 0);
        }
        float qa = q[(size_t)(rowt + row) * 8 + a];
        float4 bb = *(const float4*)(b1b + a * 64 + tq * 16 + 4 * g);
        hid[0] += qa * fabsf(a2[0] + bb.x);
        hid[1] += qa * fabsf(a2[1] + bb.y);
        hid[2] += qa * fabsf(a2[2] + bb.z);
        hid[3] += qa * fabsf(a2[3] + bb.w);
      }
      bf16x4 b1v = *(const bf16x4*)(&b1T[row * 128 + tq * 32 + 8 * g]);
      bf16x4 o;
      #pragma unroll
      for (int e = 0; e < 4; ++e) {
        float hh = hid[e] + (float)b1v[e];
        hh = hh > 0.f ? hh : (__expf(hh) - 1.f);
        o[e] = (bf16_t)hh;
      }
      *(bf16x4*)(&hidT[row * 128 + tq * 32 + 8 * g]) = o;
    }
    // write next s tile (sT free since barrier A)
    if (rt < 3) {
      *(bf16x8*)(&sT[srow * 512 + SWZ(srow, sc * 32)])      = cvt8(L0, L1);
      *(bf16x8*)(&sT[srow * 512 + SWZ(srow, sc * 32 + 16)]) = cvt8(L2, L3);
    }
    __syncthreads();  // B: hidT/w2T ready; sT[next] staged
    // ======== final: out = hidden . w2 + b2
    {
      const int row = tid >> 4, c = tid & 15;
      bf16x4 hv = *(const bf16x4*)(&hidT[row * 128 + c * 8]);
      bf16x4 wv = *(const bf16x4*)(&w2T[row * 128 + c * 8]);
      float d = (float)hv[0]*(float)wv[0] + (float)hv[1]*(float)wv[1]
              + (float)hv[2]*(float)wv[2] + (float)hv[3]*(float)wv[3];
      d += __shfl_xor(d, 1); d += __shfl_xor(d, 2);
      d += __shfl_xor(d, 4); d += __shfl_xor(d, 8);
      if (c == 0) {
        float b2v = b2part[0][row] + b2part[1][row] + b2part[2][row]
                  + b2part[3][row] + bb2b0;
        out[rowt + row] = d + b2v;
      }
    }
    __syncthreads();  // C: all tile-local buffers reusable
  }
}

extern "C" void kernel_launch(void* const* d_in, const int* in_sizes, int n_in,
                              void* d_out, int out_size, void* d_ws, size_t ws_size,
                              hipStream_t stream) {
  const float* q    = (const float*)d_in[0];
  const float* s    = (const float*)d_in[1];
  const float* W1a  = (const float*)d_in[2];
  const float* b1a  = (const float*)d_in[3];
  const float* W1b  = (const float*)d_in[4];
  const float* b1b  = (const float*)d_in[5];
  const float* W2a  = (const float*)d_in[6];
  const float* b2a  = (const float*)d_in[7];
  const float* W2b  = (const float*)d_in[8];
  const float* b2b  = (const float*)d_in[9];
  const float* Wb1  = (const float*)d_in[10];
  const float* bb1  = (const float*)d_in[11];
  const float* Wb2a = (const float*)d_in[12];
  const float* bb2a = (const float*)d_in[13];
  const float* Wb2b = (const float*)d_in[14];
  const float* bb2b = (const float*)d_in[15];
  bf16_t* ws = (bf16_t*)d_ws;
  float* out = (float*)d_out;

  int N  = in_sizes[0] / 8;       // 65536 rows
  int nb = N / 256;               // 256 blocks

  cvt_frag<<<152, 256, 0, stream>>>(W1a, W2a, W1b, W2b, Wb1, Wb2a, ws);
  qmix_f3<<<nb, 1024, 0, stream>>>(s, q, ws, b1a, b2a, b1b, b2b,
                                   bb1, bb2a, Wb2b, bb2b, out);
}

// Round 9
// 122.867 us; speedup vs baseline: 1.6809x; 1.6809x over previous
//
#include <hip/hip_runtime.h>

typedef __bf16 bf16_t;
typedef bf16_t bf16x8 __attribute__((ext_vector_type(8)));
typedef bf16_t bf16x4 __attribute__((ext_vector_type(4)));
typedef float f32x4 __attribute__((ext_vector_type(4)));
typedef float fv4 __attribute__((ext_vector_type(4)));

#define MFMA __builtin_amdgcn_mfma_f32_16x16x32_bf16
#define SWZ(row, off) ((off) ^ (((row) & 7) << 4))

// ws: weights in MFMA A-fragment order: elem((t*8+kk)*512 + lane*8 + j)
//   = W[k = kk*32 + (lane>>4)*8 + j][col = t*16 + (lane&15)]
#define F_W1A   0        // 256 cols (16 tiles)
#define F_W2A   65536    // 256 cols
#define F_W1B   131072   // 512 cols (tile idx = agent*4 + qhtile)
#define F_W2B   262144   // 64 cols (4 tiles)
#define F_WB1   278528   // 64 cols
#define F_WB2A  294912   // 64 cols

__device__ __forceinline__ bf16x8 cvt8(fv4 a, fv4 b) {
  bf16x8 v;
  v[0]=(bf16_t)a[0]; v[1]=(bf16_t)a[1]; v[2]=(bf16_t)a[2]; v[3]=(bf16_t)a[3];
  v[4]=(bf16_t)b[0]; v[5]=(bf16_t)b[1]; v[6]=(bf16_t)b[2]; v[7]=(bf16_t)b[3];
  return v;
}

__global__ __launch_bounds__(256) void cvt_frag(
    const float* __restrict__ W1a, const float* __restrict__ W2a,
    const float* __restrict__ W1b, const float* __restrict__ W2b,
    const float* __restrict__ Wb1, const float* __restrict__ Wb2a,
    bf16_t* __restrict__ ws)
{
  int gid = blockIdx.x * 256 + threadIdx.x;
  const float* src; int start, base, nout;
  if (gid < 8192)       { src = W1a;  start = 0;     base = F_W1A;  nout = 256; }
  else if (gid < 16384) { src = W2a;  start = 8192;  base = F_W2A;  nout = 256; }
  else if (gid < 32768) { src = W1b;  start = 16384; base = F_W1B;  nout = 512; }
  else if (gid < 34816) { src = W2b;  start = 32768; base = F_W2B;  nout = 64;  }
  else if (gid < 36864) { src = Wb1;  start = 34816; base = F_WB1;  nout = 64;  }
  else                  { src = Wb2a; start = 36864; base = F_WB2A; nout = 64;  }
  int local = gid - start;
  int t = local >> 9, kk = (local >> 6) & 7, l = local & 63;
  int n  = t * 16 + (l & 15);
  int k0 = kk * 32 + (l >> 4) * 8;
  bf16x8 v;
  #pragma unroll
  for (int j = 0; j < 8; ++j) v[j] = (bf16_t)src[(k0 + j) * nout + n];
  *(bf16x8*)(ws + base + (size_t)local * 8) = v;
}

#define FRAG(base, tile, kk) \
  (*(const bf16x8*)(ws + (base) + ((size_t)(((tile) * 8 + (kk))) << 9) + lane * 8))

// fused: 512 thr (8 waves), 256 rows/block, 4 x 64-row tiles, 1 block/CU.
// No forced occupancy bound -> compiler free to use ~160-190 regs, no spill.
__global__ __launch_bounds__(512) void qmix_f4(
    const float* __restrict__ s, const float* __restrict__ q,
    const bf16_t* __restrict__ ws,
    const float* __restrict__ b1a, const float* __restrict__ b2a,
    const float* __restrict__ b1b, const float* __restrict__ b2b,
    const float* __restrict__ bb1, const float* __restrict__ bb2a,
    const float* __restrict__ Wb2b, const float* __restrict__ bb2b,
    float* __restrict__ out)
{
  __shared__ __align__(16) char sT[64 * 512];      // 32K s tile (bf16, swizzled)
  __shared__ __align__(16) char h1T[64 * 512];     // 32K
  __shared__ __align__(16) char h2T[64 * 512];     // 32K
  __shared__ __align__(16) char b1T[64 * 128];     // 8K  [row][qh] bf16
  __shared__ __align__(16) char w2T[64 * 128];     // 8K
  __shared__ __align__(16) char hidT[2][64 * 256]; // 32K f32 partial hidden
  __shared__ float b2part[4][64];                  // 1K   -> 145K total

  const int tid = threadIdx.x, wave = tid >> 6, lane = tid & 63;
  const int r16 = lane & 15, g = lane >> 4;
  const int row0 = blockIdx.x * 256;
  const int srow = tid >> 3, sc = tid & 7;         // 64 rows x 8 chunks x 32 floats

  // prologue: stage s tile 0
  {
    const fv4* p = (const fv4*)(s + (size_t)(row0 + srow) * 256 + sc * 32);
    #pragma unroll
    for (int j = 0; j < 4; ++j) {
      fv4 a = __builtin_nontemporal_load(p + j * 2);
      fv4 b = __builtin_nontemporal_load(p + j * 2 + 1);
      *(bf16x8*)(&sT[srow * 512 + SWZ(srow, sc * 64 + j * 16)]) = cvt8(a, b);
    }
  }
  __syncthreads();

  const float bb2b0 = bb2b[0];
  const int smBase = (wave < 4) ? (F_WB1 + wave * 4096) : (F_WB2A + (wave - 4) * 4096);

  #pragma unroll 1
  for (int rt = 0; rt < 4; ++rt) {
    const int rowt = row0 + rt * 64;
    // ======== phase 1, pass A: h1 = relu(s @ W1a + b1a)  (tiles wave, wave+8)
    {
      f32x4 acc[2][4];
      #pragma unroll
      for (int t = 0; t < 2; ++t)
        #pragma unroll
        for (int h = 0; h < 4; ++h) acc[t][h] = (f32x4)0.f;
      #pragma unroll 2
      for (int kk = 0; kk < 8; ++kk) {
        bf16x8 A0 = FRAG(F_W1A, wave, kk);
        bf16x8 A1 = FRAG(F_W1A, wave + 8, kk);
        #pragma unroll
        for (int h = 0; h < 4; ++h) {
          int rr = h * 16 + r16;
          bf16x8 B = *(const bf16x8*)(&sT[rr * 512 + SWZ(rr, kk * 64 + g * 16)]);
          acc[0][h] = MFMA(A0, B, acc[0][h], 0, 0, 0);
          acc[1][h] = MFMA(A1, B, acc[1][h], 0, 0, 0);
        }
      }
      #pragma unroll
      for (int t8 = 0; t8 < 2; ++t8) {
        float4 bh = *(const float4*)(b1a + (wave + t8 * 8) * 16 + 4 * g);
        #pragma unroll
        for (int h = 0; h < 4; ++h) {
          int rr = h * 16 + r16;
          f32x4 x = acc[t8][h];
          bf16x4 v;
          v[0]=(bf16_t)fmaxf(x[0]+bh.x,0.f); v[1]=(bf16_t)fmaxf(x[1]+bh.y,0.f);
          v[2]=(bf16_t)fmaxf(x[2]+bh.z,0.f); v[3]=(bf16_t)fmaxf(x[3]+bh.w,0.f);
          *(bf16x4*)(&h1T[rr * 512 + SWZ(rr, (wave + t8 * 8) * 32 + 8 * g)]) = v;
        }
      }
    }
    // ======== phase 1, pass B: h2 = relu(s @ W2a + b2a)
    {
      f32x4 acc[2][4];
      #pragma unroll
      for (int t = 0; t < 2; ++t)
        #pragma unroll
        for (int h = 0; h < 4; ++h) acc[t][h] = (f32x4)0.f;
      #pragma unroll 2
      for (int kk = 0; kk < 8; ++kk) {
        bf16x8 A0 = FRAG(F_W2A, wave, kk);
        bf16x8 A1 = FRAG(F_W2A, wave + 8, kk);
        #pragma unroll
        for (int h = 0; h < 4; ++h) {
          int rr = h * 16 + r16;
          bf16x8 B = *(const bf16x8*)(&sT[rr * 512 + SWZ(rr, kk * 64 + g * 16)]);
          acc[0][h] = MFMA(A0, B, acc[0][h], 0, 0, 0);
          acc[1][h] = MFMA(A1, B, acc[1][h], 0, 0, 0);
        }
      }
      #pragma unroll
      for (int t8 = 0; t8 < 2; ++t8) {
        float4 bh = *(const float4*)(b2a + (wave + t8 * 8) * 16 + 4 * g);
        #pragma unroll
        for (int h = 0; h < 4; ++h) {
          int rr = h * 16 + r16;
          f32x4 x = acc[t8][h];
          bf16x4 v;
          v[0]=(bf16_t)fmaxf(x[0]+bh.x,0.f); v[1]=(bf16_t)fmaxf(x[1]+bh.y,0.f);
          v[2]=(bf16_t)fmaxf(x[2]+bh.z,0.f); v[3]=(bf16_t)fmaxf(x[3]+bh.w,0.f);
          *(bf16x4*)(&h2T[rr * 512 + SWZ(rr, (wave + t8 * 8) * 32 + 8 * g)]) = v;
        }
      }
    }
    // ======== phase 1, pass C: smalls (Wb1 -> b1T | Wb2a-chain -> b2part)
    {
      f32x4 aS[4];
      #pragma unroll
      for (int h = 0; h < 4; ++h) aS[h] = (f32x4)0.f;
      #pragma unroll
      for (int kk = 0; kk < 8; ++kk) {
        bf16x8 A = *(const bf16x8*)(ws + smBase + ((size_t)kk << 9) + lane * 8);
        #pragma unroll
        for (int h = 0; h < 4; ++h) {
          int rr = h * 16 + r16;
          bf16x8 B = *(const bf16x8*)(&sT[rr * 512 + SWZ(rr, kk * 64 + g * 16)]);
          aS[h] = MFMA(A, B, aS[h], 0, 0, 0);
        }
      }
      if (wave < 4) {
        float4 bb = *(const float4*)(bb1 + wave * 16 + 4 * g);
        #pragma unroll
        for (int h = 0; h < 4; ++h) {
          int rr = h * 16 + r16;
          bf16x4 o;
          o[0]=(bf16_t)(aS[h][0]+bb.x); o[1]=(bf16_t)(aS[h][1]+bb.y);
          o[2]=(bf16_t)(aS[h][2]+bb.z); o[3]=(bf16_t)(aS[h][3]+bb.w);
          *(bf16x4*)(&b1T[rr * 128 + wave * 32 + 8 * g]) = o;
        }
      } else {
        float4 ba = *(const float4*)(bb2a + (wave - 4) * 16 + 4 * g);
        float4 wv = *(const float4*)(Wb2b + (wave - 4) * 16 + 4 * g);
        #pragma unroll
        for (int h = 0; h < 4; ++h) {
          int rr = h * 16 + r16;
          f32x4 x = aS[h];
          float part = fmaxf(x[0]+ba.x,0.f)*wv.x + fmaxf(x[1]+ba.y,0.f)*wv.y
                     + fmaxf(x[2]+ba.z,0.f)*wv.z + fmaxf(x[3]+ba.w,0.f)*wv.w;
          part += __shfl_xor(part, 16); part += __shfl_xor(part, 32);
          if (lane < 16) b2part[wave - 4][rr] = part;
        }
      }
    }
    __syncthreads();  // A: h1T/h2T/b1T/b2part ready; sT free

    // issue next s-tile loads (latency hides under phase 2 MFMAs)
    fv4 pf[8];
    if (rt < 3) {
      const fv4* p = (const fv4*)(s + (size_t)(rowt + 64 + srow) * 256 + sc * 32);
      #pragma unroll
      for (int j = 0; j < 8; ++j) pf[j] = __builtin_nontemporal_load(p + j);
    }
    // ======== phase 2a: w2 = |h2 @ W2b + b2b|  (tile tq, row-halves hs)
    {
      const int tq = wave & 3, hs = wave >> 2;
      f32x4 av[2]; av[0] = (f32x4)0.f; av[1] = (f32x4)0.f;
      #pragma unroll
      for (int kk = 0; kk < 8; ++kk) {
        bf16x8 A = FRAG(F_W2B, tq, kk);
        #pragma unroll
        for (int hh = 0; hh < 2; ++hh) {
          int rr = hs * 32 + hh * 16 + r16;
          bf16x8 B = *(const bf16x8*)(&h2T[rr * 512 + SWZ(rr, kk * 64 + g * 16)]);
          av[hh] = MFMA(A, B, av[hh], 0, 0, 0);
        }
      }
      float4 bv = *(const float4*)(b2b + tq * 16 + 4 * g);
      #pragma unroll
      for (int hh = 0; hh < 2; ++hh) {
        int rr = hs * 32 + hh * 16 + r16;
        bf16x4 o;
        o[0]=(bf16_t)fabsf(av[hh][0]+bv.x); o[1]=(bf16_t)fabsf(av[hh][1]+bv.y);
        o[2]=(bf16_t)fabsf(av[hh][2]+bv.z); o[3]=(bf16_t)fabsf(av[hh][3]+bv.w);
        *(bf16x4*)(&w2T[rr * 128 + tq * 32 + 8 * g]) = o;
      }
    }
    // ======== phase 2b: partial hidden (qh-tile tq, agent-half ah), all rows
    {
      const int tq = wave & 3, ah = wave >> 2;
      #pragma unroll 1
      for (int h = 0; h < 4; ++h) {
        const int rr = h * 16 + r16;
        bf16x8 B[8];
        #pragma unroll
        for (int kk = 0; kk < 8; ++kk)
          B[kk] = *(const bf16x8*)(&h1T[rr * 512 + SWZ(rr, kk * 64 + g * 16)]);
        f32x4 hid = (f32x4)0.f;
        #pragma unroll 2
        for (int aa = 0; aa < 4; ++aa) {
          const int a = ah * 4 + aa;
          f32x4 a2 = (f32x4)0.f;
          #pragma unroll
          for (int kk = 0; kk < 8; ++kk) {
            bf16x8 A = FRAG(F_W1B, a * 4 + tq, kk);
            a2 = MFMA(A, B[kk], a2, 0, 0, 0);
          }
          float qa = q[(size_t)(rowt + rr) * 8 + a];
          float4 bb = *(const float4*)(b1b + a * 64 + tq * 16 + 4 * g);
          hid[0] += qa * fabsf(a2[0] + bb.x);
          hid[1] += qa * fabsf(a2[1] + bb.y);
          hid[2] += qa * fabsf(a2[2] + bb.z);
          hid[3] += qa * fabsf(a2[3] + bb.w);
        }
        *(f32x4*)(&hidT[ah][rr * 256 + SWZ(rr, tq * 64 + g * 16)]) = hid;
      }
    }
    // write next s tile (sT free since barrier A)
    if (rt < 3) {
      #pragma unroll
      for (int j = 0; j < 4; ++j)
        *(bf16x8*)(&sT[srow * 512 + SWZ(srow, sc * 64 + j * 16)]) =
            cvt8(pf[j * 2], pf[j * 2 + 1]);
    }
    __syncthreads();  // B: hidT/w2T ready; sT[next] staged
    // ======== final: hidden = elu(hid0+hid1+b1); out = hidden.w2 + b2
    {
      const int row = tid >> 3, c = tid & 7;
      f32x4 sA0 = *(const f32x4*)(&hidT[0][row * 256 + SWZ(row, c * 32)]);
      f32x4 sA1 = *(const f32x4*)(&hidT[0][row * 256 + SWZ(row, c * 32 + 16)]);
      f32x4 sB0 = *(const f32x4*)(&hidT[1][row * 256 + SWZ(row, c * 32)]);
      f32x4 sB1 = *(const f32x4*)(&hidT[1][row * 256 + SWZ(row, c * 32 + 16)]);
      bf16x8 b1v = *(const bf16x8*)(&b1T[row * 128 + c * 16]);
      bf16x8 wv  = *(const bf16x8*)(&w2T[row * 128 + c * 16]);
      float d = 0.f;
      #pragma unroll
      for (int e = 0; e < 4; ++e) {
        float h0 = sA0[e] + sB0[e] + (float)b1v[e];
        float h1 = sA1[e] + sB1[e] + (float)b1v[4 + e];
        h0 = h0 > 0.f ? h0 : (__expf(h0) - 1.f);
        h1 = h1 > 0.f ? h1 : (__expf(h1) - 1.f);
        d += h0 * (float)wv[e] + h1 * (float)wv[4 + e];
      }
      d += __shfl_xor(d, 1); d += __shfl_xor(d, 2); d += __shfl_xor(d, 4);
      if (c == 0) {
        float b2v = b2part[0][row] + b2part[1][row] + b2part[2][row]
                  + b2part[3][row] + bb2b0;
        out[rowt + row] = d + b2v;
      }
    }
    __syncthreads();  // C: tile-local buffers reusable
  }
}

extern "C" void kernel_launch(void* const* d_in, const int* in_sizes, int n_in,
                              void* d_out, int out_size, void* d_ws, size_t ws_size,
                              hipStream_t stream) {
  const float* q    = (const float*)d_in[0];
  const float* s    = (const float*)d_in[1];
  const float* W1a  = (const float*)d_in[2];
  const float* b1a  = (const float*)d_in[3];
  const float* W1b  = (const float*)d_in[4];
  const float* b1b  = (const float*)d_in[5];
  const float* W2a  = (const float*)d_in[6];
  const float* b2a  = (const float*)d_in[7];
  const float* W2b  = (const float*)d_in[8];
  const float* b2b  = (const float*)d_in[9];
  const float* Wb1  = (const float*)d_in[10];
  const float* bb1  = (const float*)d_in[11];
  const float* Wb2a = (const float*)d_in[12];
  const float* bb2a = (const float*)d_in[13];
  const float* Wb2b = (const float*)d_in[14];
  const float* bb2b = (const float*)d_in[15];
  bf16_t* ws = (bf16_t*)d_ws;
  float* out = (float*)d_out;

  int N  = in_sizes[0] / 8;       // 65536 rows
  int nb = N / 256;               // 256 blocks

  cvt_frag<<<152, 256, 0, stream>>>(W1a, W2a, W1b, W2b, Wb1, Wb2a, ws);
  qmix_f4<<<nb, 512, 0, stream>>>(s, q, ws, b1a, b2a, b1b, b2b,
                                  bb1, bb2a, Wb2b, bb2b, out);
}